// Round 1
// baseline (329.832 us; speedup 1.0000x reference)
//
#include <hip/hip_runtime.h>
#include <hip/hip_fp16.h>

typedef float  f32x4 __attribute__((ext_vector_type(4)));
typedef _Float16 f16x8 __attribute__((ext_vector_type(8)));
typedef _Float16 f16x4 __attribute__((ext_vector_type(4)));

#define NB     512      // N
#define DD     64       // D
#define HT_ST  520      // f16 row stride (512 + 8 pad): 16B-aligned rows, bank-spread
#define NCHUNK 4        // 4 chunks of 32 rows = 128 rows per block

__device__ __forceinline__ int binidx(float heading, float bearing) {
    float sh = heading + 15.0f; sh = (sh >= 360.0f) ? sh - 360.0f : sh;
    float sb = bearing + 15.0f; sb = (sb >= 360.0f) ? sb - 360.0f : sb;
    int ih = (int)floorf(sh / 30.0f); ih = min(max(ih, 0), 11);
    int ib = (int)floorf(sb / 30.0f); ib = min(max(ib, 0), 11);
    return ih * 12 + ib;
}

// max-normalize -> masked softmax -> f16 store of one row (w distributed: lane has
// j = 4*lane..4*lane+3 (wA) and 256+4*lane..+3 (wB))
__device__ __forceinline__ void finish_and_store(f32x4 wA, f32x4 wB, _Float16* dst, int lane) {
    float mx = fmaxf(fmaxf(fmaxf(wA[0], wA[1]), fmaxf(wA[2], wA[3])),
                     fmaxf(fmaxf(wB[0], wB[1]), fmaxf(wB[2], wB[3])));
    #pragma unroll
    for (int off = 1; off < 64; off <<= 1) mx = fmaxf(mx, __shfl_xor(mx, off));
    const float rinv = 1.0f / (mx + 1e-14f);
    f32x4 eA, eB; float s = 0.0f;
    #pragma unroll
    for (int t = 0; t < 4; ++t) {
        float wn = wA[t] * rinv;
        eA[t] = (wn != 0.0f) ? __expf(wn) : 0.0f;
        wn = wB[t] * rinv;
        eB[t] = (wn != 0.0f) ? __expf(wn) : 0.0f;
        s += eA[t] + eB[t];
    }
    #pragma unroll
    for (int off = 1; off < 64; off <<= 1) s += __shfl_xor(s, off);
    const float g = (s != 0.0f) ? (1.0f / (s + 1e-14f)) : 0.0f;
    f16x4 ha, hb;
    #pragma unroll
    for (int t = 0; t < 4; ++t) {
        ha[t] = (_Float16)(eA[t] * g);
        hb[t] = (_Float16)(eB[t] * g);
    }
    *(f16x4*)(dst + 4 * lane)       = ha;
    *(f16x4*)(dst + 256 + 4 * lane) = hb;
}

__global__ __launch_bounds__(1024, 1) void spatial_attn_kernel(
    const float* __restrict__ hid,
    const float* __restrict__ dist,
    const float* __restrict__ bear,
    const float* __restrict__ head,
    const float* __restrict__ mask,
    const float* __restrict__ dom,
    float* __restrict__ out)
{
    __shared__ __align__(16) _Float16 sHT[DD * HT_ST];       // hidden^T, f16: [d][k]
    __shared__ __align__(16) _Float16 sW[2][32 * HT_ST];     // double-buffered W tile (32 rows)
    __shared__ __align__(16) float sMask[NB];
    __shared__ __align__(16) float sDom[144];
    __shared__ float sDomVal;
    __shared__ int   sUni;

    const int tid  = threadIdx.x;
    const int lane = tid & 63;
    const int wid  = tid >> 6;          // 0..15
    const int l16  = lane & 15;
    const int lg   = lane >> 4;         // 0..3
    const int b      = blockIdx.x >> 2;
    const int i0blk  = (blockIdx.x & 3) << 7;   // 0,128,256,384

    if (tid < NB)  sMask[tid] = mask[b * NB + tid];
    if (tid < 144) sDom[tid]  = dom[tid];
    __syncthreads();
    if (tid == 0) {
        float v = sDom[0];
        int u = 1;
        for (int t = 1; t < 144; ++t) u &= (sDom[t] == v) ? 1 : 0;
        sUni = u; sDomVal = v;
    }

    // ---- stage hidden^T (f16) into LDS + copy hidden -> out[:,64:128] ----
    {
        const int d4 = tid & 15;         // float4 column (d = 4*d4..4*d4+3)
        const int jg = tid >> 4;         // 0..63
        const f32x4* hid4 = (const f32x4*)(hid + (size_t)b * NB * DD);
        #pragma unroll
        for (int it = 0; it < 2; ++it) {
            const int j0 = 4 * jg + 256 * it;
            f32x4 v0 = hid4[(j0 + 0) * 16 + d4];
            f32x4 v1 = hid4[(j0 + 1) * 16 + d4];
            f32x4 v2 = hid4[(j0 + 2) * 16 + d4];
            f32x4 v3 = hid4[(j0 + 3) * 16 + d4];
            *(f32x4*)(out + (size_t)(b * NB + j0 + 0) * 128 + 64 + 4 * d4) = v0;
            *(f32x4*)(out + (size_t)(b * NB + j0 + 1) * 128 + 64 + 4 * d4) = v1;
            *(f32x4*)(out + (size_t)(b * NB + j0 + 2) * 128 + 64 + 4 * d4) = v2;
            *(f32x4*)(out + (size_t)(b * NB + j0 + 3) * 128 + 64 + 4 * d4) = v3;
            #pragma unroll
            for (int c = 0; c < 4; ++c) {   // 4x4 micro-transpose
                f16x4 hv;
                hv[0] = (_Float16)v0[c]; hv[1] = (_Float16)v1[c];
                hv[2] = (_Float16)v2[c]; hv[3] = (_Float16)v3[c];
                *(f16x4*)&sHT[(4 * d4 + c) * HT_ST + j0] = hv;
            }
        }
    }
    __syncthreads();

    const bool  uni  = (sUni != 0);
    const float domc = sDomVal;

    // ---- producer(waves 0-7) / consumer(waves 8-15) pipeline over 4 chunks ----
    for (int step = 0; step <= NCHUNK; ++step) {
        if (wid < 8) {
            if (step < NCHUNK) {
                _Float16* wbuf = sW[step & 1];
                const int ibase = i0blk + step * 32 + wid * 4;   // 4 rows per wave
                const f32x4 ma4 = *(const f32x4*)(sMask + 4 * lane);
                const f32x4 mb4 = *(const f32x4*)(sMask + 256 + 4 * lane);
                if (uni) {
                    f32x4 DA[4], DB[4];
                    #pragma unroll
                    for (int q = 0; q < 4; ++q) {
                        const float* dp = dist + (size_t)(b * NB + ibase + q) * NB;
                        DA[q] = *(const f32x4*)(dp + 4 * lane);
                        DB[q] = *(const f32x4*)(dp + 256 + 4 * lane);
                    }
                    #pragma unroll
                    for (int q = 0; q < 4; ++q) {
                        const int i = ibase + q;
                        const float mi = sMask[i];
                        f32x4 wA, wB;
                        #pragma unroll
                        for (int t = 0; t < 4; ++t) {
                            const int ja = 4 * lane + t;
                            const int jb = 256 + 4 * lane + t;
                            const float mma = mi * ma4[t] * ((ja != i) ? 1.0f : 0.0f);
                            const float mmb = mi * mb4[t] * ((jb != i) ? 1.0f : 0.0f);
                            wA[t] = fmaxf(domc - DA[q][t], 0.0f) * mma;
                            wB[t] = fmaxf(domc - DB[q][t], 0.0f) * mmb;
                        }
                        finish_and_store(wA, wB, wbuf + (wid * 4 + q) * HT_ST, lane);
                    }
                } else {
                    // general path: per-element domain bin gather
                    #pragma unroll 1
                    for (int q = 0; q < 4; ++q) {
                        const int i = ibase + q;
                        const size_t ro = (size_t)(b * NB + i) * NB;
                        const f32x4 da = *(const f32x4*)(dist + ro + 4 * lane);
                        const f32x4 db = *(const f32x4*)(dist + ro + 256 + 4 * lane);
                        const f32x4 ba = *(const f32x4*)(bear + ro + 4 * lane);
                        const f32x4 bb = *(const f32x4*)(bear + ro + 256 + 4 * lane);
                        const f32x4 ha = *(const f32x4*)(head + ro + 4 * lane);
                        const f32x4 hb = *(const f32x4*)(head + ro + 256 + 4 * lane);
                        const float mi = sMask[i];
                        f32x4 wA, wB;
                        #pragma unroll
                        for (int t = 0; t < 4; ++t) {
                            const int ja = 4 * lane + t;
                            const int jb = 256 + 4 * lane + t;
                            const float mma = mi * ma4[t] * ((ja != i) ? 1.0f : 0.0f);
                            const float mmb = mi * mb4[t] * ((jb != i) ? 1.0f : 0.0f);
                            wA[t] = fmaxf(sDom[binidx(ha[t], ba[t])] - da[t], 0.0f) * mma;
                            wB[t] = fmaxf(sDom[binidx(hb[t], bb[t])] - db[t], 0.0f) * mmb;
                        }
                        finish_and_store(wA, wB, wbuf + (wid * 4 + q) * HT_ST, lane);
                    }
                }
            }
        } else {
            if (step > 0) {
                const int chunk = step - 1;
                const _Float16* wbuf = sW[chunk & 1];
                const int cw = wid - 8;
                const int m = cw >> 2;          // 0..1 (16-row frag)
                const int n = cw & 3;           // 0..3 (16-col frag)
                f32x4 acc = {0.0f, 0.0f, 0.0f, 0.0f};
                const _Float16* aBase = wbuf + (m * 16 + l16) * HT_ST + 8 * lg;
                const _Float16* bBase = sHT  + (n * 16 + l16) * HT_ST + 8 * lg;
                #pragma unroll
                for (int k0 = 0; k0 < NB; k0 += 32) {
                    const f16x8 af = *(const f16x8*)(aBase + k0);
                    const f16x8 bf = *(const f16x8*)(bBase + k0);
                    acc = __builtin_amdgcn_mfma_f32_16x16x32_f16(af, bf, acc, 0, 0, 0);
                }
                const int irow = i0blk + chunk * 32 + m * 16 + 4 * lg;
                float* op = out + (size_t)(b * NB + irow) * 128 + n * 16 + l16;
                #pragma unroll
                for (int r = 0; r < 4; ++r) op[(size_t)r * 128] = acc[r];
            }
        }
        __syncthreads();
    }
}

extern "C" void kernel_launch(void* const* d_in, const int* in_sizes, int n_in,
                              void* d_out, int out_size, void* d_ws, size_t ws_size,
                              hipStream_t stream) {
    (void)in_sizes; (void)n_in; (void)d_ws; (void)ws_size; (void)out_size;
    const float* hid  = (const float*)d_in[0];
    const float* dist = (const float*)d_in[1];
    const float* bear = (const float*)d_in[2];
    const float* head = (const float*)d_in[3];
    const float* mask = (const float*)d_in[4];
    const float* dom  = (const float*)d_in[5];
    float* out = (float*)d_out;
    hipLaunchKernelGGL(spatial_attn_kernel, dim3(512), dim3(1024), 0, stream,
                       hid, dist, bear, head, mask, dom, out);
}